// Round 2
// baseline (247.556 us; speedup 1.0000x reference)
//
#include <hip/hip_runtime.h>
#include <hip/hip_bf16.h>

#define NROW 8192
#define NDIM 128

typedef __attribute__((ext_vector_type(8))) short short8;
typedef __attribute__((ext_vector_type(4))) float f32x4;

// Monotone float<->uint map so atomicMin/atomicMax on uint implement fp min/max.
__device__ __forceinline__ unsigned f2u_mono(float f) {
  unsigned u = __float_as_uint(f);
  return (u & 0x80000000u) ? ~u : (u | 0x80000000u);
}
__device__ __forceinline__ float u2f_mono(unsigned u) {
  return __uint_as_float((u & 0x80000000u) ? (u ^ 0x80000000u) : ~u);
}
__device__ __forceinline__ unsigned short f2bf(float f) {  // RTN fp32->bf16
  unsigned u = __float_as_uint(f);
  u += 0x7fffu + ((u >> 16) & 1u);
  return (unsigned short)(u >> 16);
}

__global__ __launch_bounds__(256) void k_convert(const float* __restrict__ e,
                                                 unsigned short* __restrict__ h) {
  int i = (blockIdx.x * 256 + threadIdx.x) * 8;
  float4 f0 = *reinterpret_cast<const float4*>(e + i);
  float4 f1 = *reinterpret_cast<const float4*>(e + i + 4);
  ushort4 a, b;
  a.x = f2bf(f0.x); a.y = f2bf(f0.y); a.z = f2bf(f0.z); a.w = f2bf(f0.w);
  b.x = f2bf(f1.x); b.y = f2bf(f1.y); b.z = f2bf(f1.z); b.w = f2bf(f1.w);
  *reinterpret_cast<ushort4*>(h + i) = a;
  *reinterpret_cast<ushort4*>(h + i + 4) = b;
}

// LDS-free fused sim-tile GEMM + per-row masked reductions.
// E (bf16, 2MB) is L2-resident; MFMA fragments load straight from global.
// Each fragment load: 16 rows x 16B at stride 256B, 4 lane-groups cover
// adjacent 16B chunks of the SAME rows -> 16 fully-used 64B lines/instr.
// Swapped orientation: acc[m][n][r] = sim[rowBase + wr*64 + n*16 + (lane&15)]
//                                        [colBase + wc*64 + m*16 + (lane>>4)*4 + r]
// -> each lane's 16 values (m x r) share ONE output row; row reduce =
//    local + shfl_xor(16) + shfl_xor(32) (reduces across the 4 g-groups).
template <int PASS>
__global__ __launch_bounds__(256, 3) void k_sim(
    const unsigned short* __restrict__ eh, const int* __restrict__ labels,
    unsigned* __restrict__ pminu, unsigned* __restrict__ nmaxu,
    float* __restrict__ sums /* [4][NROW]: ap,hp,an,hn */) {
  const int t = threadIdx.x;
  const int lane = t & 63;
  const int wid = t >> 6;
  const int wr = wid >> 1;
  const int wc = wid & 1;
  const int g = lane >> 4;
  const int l15 = lane & 15;
  const int rowBase = blockIdx.y * 128;
  const int colBase = blockIdx.x * 128;

  const char* base = reinterpret_cast<const char*>(eh);
  const char* pa[4];  // A operand: col-tile rows
  const char* pb[4];  // B operand: row-tile rows
#pragma unroll
  for (int m = 0; m < 4; ++m)
    pa[m] = base + (size_t)(colBase + wc * 64 + m * 16 + l15) * 256 + g * 16;
#pragma unroll
  for (int n = 0; n < 4; ++n)
    pb[n] = base + (size_t)(rowBase + wr * 64 + n * 16 + l15) * 256 + g * 16;

  f32x4 acc[4][4];
#pragma unroll
  for (int m = 0; m < 4; ++m)
#pragma unroll
    for (int n = 0; n < 4; ++n) acc[m][n] = (f32x4){0.f, 0.f, 0.f, 0.f};

#pragma unroll
  for (int kk = 0; kk < 4; ++kk) {
    short8 av[4], bv[4];
#pragma unroll
    for (int m = 0; m < 4; ++m)
      av[m] = *reinterpret_cast<const short8*>(pa[m] + kk * 64);
#pragma unroll
    for (int n = 0; n < 4; ++n)
      bv[n] = *reinterpret_cast<const short8*>(pb[n] + kk * 64);
#pragma unroll
    for (int m = 0; m < 4; ++m)
#pragma unroll
      for (int n = 0; n < 4; ++n)
        acc[m][n] = __builtin_amdgcn_mfma_f32_16x16x32_bf16(av[m], bv[n], acc[m][n], 0, 0, 0);
  }

  // column labels, vectorized: 4 x int4 (16B-aligned: offset multiple of 4 ints)
  int lcv[4][4];
#pragma unroll
  for (int m = 0; m < 4; ++m) {
    int4 lv = *reinterpret_cast<const int4*>(labels + colBase + wc * 64 + m * 16 + g * 4);
    lcv[m][0] = lv.x; lcv[m][1] = lv.y; lcv[m][2] = lv.z; lcv[m][3] = lv.w;
  }

  const bool diag = (rowBase == colBase);  // only 64/4096 blocks need the dg check

#pragma unroll
  for (int n = 0; n < 4; ++n) {
    const int grow = rowBase + wr * 64 + n * 16 + l15;
    const int lr = labels[grow];
    if (PASS == 1) {
      float pmin = INFINITY, nmax = -INFINITY;
      if (diag) {
#pragma unroll
        for (int m = 0; m < 4; ++m)
#pragma unroll
          for (int r = 0; r < 4; ++r) {
            float s = acc[m][n][r];
            bool eq = (lr == lcv[m][r]);
            bool dg = (grow == colBase + wc * 64 + m * 16 + g * 4 + r);
            if (eq && !dg) pmin = fminf(pmin, s);
            if (!eq) nmax = fmaxf(nmax, s);
          }
      } else {
#pragma unroll
        for (int m = 0; m < 4; ++m)
#pragma unroll
          for (int r = 0; r < 4; ++r) {
            float s = acc[m][n][r];
            bool eq = (lr == lcv[m][r]);
            if (eq) pmin = fminf(pmin, s);
            else nmax = fmaxf(nmax, s);
          }
      }
      pmin = fminf(pmin, __shfl_xor(pmin, 16));
      pmin = fminf(pmin, __shfl_xor(pmin, 32));
      nmax = fmaxf(nmax, __shfl_xor(nmax, 16));
      nmax = fmaxf(nmax, __shfl_xor(nmax, 32));
      if (g == 0 && pmin < INFINITY) atomicMin(&pminu[grow], f2u_mono(pmin));
      if (g == 1 && nmax > -INFINITY) atomicMax(&nmaxu[grow], f2u_mono(nmax));
    } else {
      // untouched rows decode to NaN -> comparisons false -> hard sums stay 0 (fallback)
      const float pmin = u2f_mono(pminu[grow]);
      const float nmax = u2f_mono(nmaxu[grow]);
      const float thrp = nmax + 0.1f;  // pos_hard: s - MARGIN < neg_max
      const float thrn = pmin - 0.1f;  // neg_hard: s + MARGIN > pos_min
      float ap = 0.f, hp = 0.f, an = 0.f, hn = 0.f;
      if (diag) {
#pragma unroll
        for (int m = 0; m < 4; ++m)
#pragma unroll
          for (int r = 0; r < 4; ++r) {
            float s = acc[m][n][r];
            bool eq = (lr == lcv[m][r]);
            bool dg = (grow == colBase + wc * 64 + m * 16 + g * 4 + r);
            float ep = exp2f(fmaf(s, -2.885390082f, 1.442695041f));   // exp(-2(s-.5))
            float en = exp2f(fmaf(s, 72.13475205f, -36.06737602f));   // exp(50(s-.5))
            if (eq) {
              if (!dg) { ap += ep; if (s < thrp) hp += ep; }
            } else {
              an += en; if (s > thrn) hn += en;
            }
          }
      } else {
#pragma unroll
        for (int m = 0; m < 4; ++m)
#pragma unroll
          for (int r = 0; r < 4; ++r) {
            float s = acc[m][n][r];
            bool eq = (lr == lcv[m][r]);
            float ep = exp2f(fmaf(s, -2.885390082f, 1.442695041f));
            float en = exp2f(fmaf(s, 72.13475205f, -36.06737602f));
            if (eq) {
              ap += ep; if (s < thrp) hp += ep;
            } else {
              an += en; if (s > thrn) hn += en;
            }
          }
      }
      ap += __shfl_xor(ap, 16); ap += __shfl_xor(ap, 32);
      hp += __shfl_xor(hp, 16); hp += __shfl_xor(hp, 32);
      an += __shfl_xor(an, 16); an += __shfl_xor(an, 32);
      hn += __shfl_xor(hn, 16); hn += __shfl_xor(hn, 32);
      // after the butterfly all 4 g-lanes hold the row totals: one atomic per lane
      float v = (g == 0) ? ap : (g == 1) ? hp : (g == 2) ? an : hn;
      if (v > 0.f) atomicAdd(sums + g * NROW + grow, v);
    }
  }
}

__global__ __launch_bounds__(256) void k_final(const float* __restrict__ sums,
                                               float* __restrict__ out) {
  const int t = threadIdx.x;
  float acc = 0.f, cnt = 0.f;
  for (int i = t; i < NROW; i += 256) {
    float ap = sums[i], hp = sums[NROW + i], an = sums[2 * NROW + i], hn = sums[3 * NROW + i];
    bool valid = (ap > 0.f) && (an > 0.f);
    float ps = (hp > 0.f) ? hp : ap;
    float ns = (hn > 0.f) ? hn : an;
    float loss = 0.5f * log1pf(ps) + 0.02f * log1pf(ns);
    if (valid) { acc += loss; cnt += 1.f; }
  }
#pragma unroll
  for (int o = 32; o > 0; o >>= 1) {
    acc += __shfl_down(acc, o);
    cnt += __shfl_down(cnt, o);
  }
  __shared__ float sa[4], sc[4];
  int w = t >> 6, lane = t & 63;
  if (lane == 0) { sa[w] = acc; sc[w] = cnt; }
  __syncthreads();
  if (t == 0) {
    float A = sa[0] + sa[1] + sa[2] + sa[3];
    float C = sc[0] + sc[1] + sc[2] + sc[3];
    out[0] = A / fmaxf(C, 1.f);
  }
}

extern "C" void kernel_launch(void* const* d_in, const int* in_sizes, int n_in,
                              void* d_out, int out_size, void* d_ws, size_t ws_size,
                              hipStream_t stream) {
  const float* emb = (const float*)d_in[0];
  const int* labels = (const int*)d_in[1];
  float* out = (float*)d_out;

  // ws layout: [bf16 emb: 2MB][pminu:32K][nmaxu:32K][sums: 4x32K]
  unsigned short* embh = (unsigned short*)d_ws;
  unsigned* pminu = (unsigned*)((char*)d_ws + (size_t)NROW * NDIM * 2);
  unsigned* nmaxu = pminu + NROW;
  float* sums = (float*)(nmaxu + NROW);

  hipMemsetAsync(pminu, 0xFF, (size_t)NROW * 4, stream);   // mapped +inf sentinel
  hipMemsetAsync(nmaxu, 0, (size_t)NROW * 4 * 5, stream);  // nmaxu + 4 sums = 0

  k_convert<<<NROW * NDIM / (256 * 8), 256, 0, stream>>>(emb, embh);
  dim3 grid(64, 64);
  k_sim<1><<<grid, 256, 0, stream>>>(embh, labels, pminu, nmaxu, sums);
  k_sim<2><<<grid, 256, 0, stream>>>(embh, labels, pminu, nmaxu, sums);
  k_final<<<1, 256, 0, stream>>>(sums, out);
}

// Round 3
// 145.746 us; speedup vs baseline: 1.6985x; 1.6985x over previous
//
#include <hip/hip_runtime.h>
#include <hip/hip_bf16.h>

#define NROW 8192
#define NDIM 128
#define CCHUNK 8  // col tiles per block; grid = (8, 64) -> 512 blocks = 2/CU

typedef __attribute__((ext_vector_type(8))) short short8;
typedef __attribute__((ext_vector_type(4))) float f32x4;

__device__ __forceinline__ unsigned f2u_mono(float f) {
  unsigned u = __float_as_uint(f);
  return (u & 0x80000000u) ? ~u : (u | 0x80000000u);
}
__device__ __forceinline__ float u2f_mono(unsigned u) {
  return __uint_as_float((u & 0x80000000u) ? (u ^ 0x80000000u) : ~u);
}
__device__ __forceinline__ unsigned short f2bf(float f) {  // RTN fp32->bf16
  unsigned u = __float_as_uint(f);
  u += 0x7fffu + ((u >> 16) & 1u);
  return (unsigned short)(u >> 16);
}

__global__ __launch_bounds__(256) void k_convert(const float* __restrict__ e,
                                                 unsigned short* __restrict__ h) {
  int i = (blockIdx.x * 256 + threadIdx.x) * 8;
  float4 f0 = *reinterpret_cast<const float4*>(e + i);
  float4 f1 = *reinterpret_cast<const float4*>(e + i + 4);
  ushort4 a, b;
  a.x = f2bf(f0.x); a.y = f2bf(f0.y); a.z = f2bf(f0.z); a.w = f2bf(f0.w);
  b.x = f2bf(f1.x); b.y = f2bf(f1.y); b.z = f2bf(f1.z); b.w = f2bf(f1.w);
  *reinterpret_cast<ushort4*>(h + i) = a;
  *reinterpret_cast<ushort4*>(h + i + 4) = b;
}

// Column-sweep fused sim GEMM + per-row reductions, LDS-free (E bf16 is L2-resident).
// Block = 128 rows x (CCHUNK*128) cols. Row-operand fragments live in registers for
// the whole sweep; per-row reductions accumulate in registers; one atomic set/block.
// acc[m][n][r] = sim[rowBase + wr*64 + n*16 + (lane&15)]
//                   [colBase + wc*64 + m*16 + (lane>>4)*4 + r]
template <int PASS>
__global__ __launch_bounds__(256, 2) void k_sim(
    const unsigned short* __restrict__ eh, const int* __restrict__ labels,
    unsigned* __restrict__ pminu, unsigned* __restrict__ nmaxu,
    float* __restrict__ sums /* [4][NROW]: ap,hp,an,hn */) {
  const int t = threadIdx.x;
  const int lane = t & 63;
  const int wid = t >> 6;
  const int wr = wid >> 1;
  const int wc = wid & 1;
  const int g = lane >> 4;
  const int l15 = lane & 15;
  const int rowBase = blockIdx.y * 128;
  const int colChunk = blockIdx.x;

  // row-operand fragments (B), held in registers for the entire sweep
  short8 bv[4][4];  // [kk][n]
  int grow[4], lr[4];
#pragma unroll
  for (int n = 0; n < 4; ++n) {
    grow[n] = rowBase + wr * 64 + n * 16 + l15;
    lr[n] = labels[grow[n]];
#pragma unroll
    for (int kk = 0; kk < 4; ++kk)
      bv[kk][n] = *reinterpret_cast<const short8*>(eh + (size_t)grow[n] * NDIM + kk * 32 + g * 8);
  }

  // per-row running state (registers, combined once at block end)
  float pminA[4], nmaxA[4];                      // PASS1
  float ap[4], hp[4], an[4], hn[4];              // PASS2
  float thrp[4], thrn[4];
#pragma unroll
  for (int n = 0; n < 4; ++n) {
    pminA[n] = INFINITY; nmaxA[n] = -INFINITY;
    ap[n] = hp[n] = an[n] = hn[n] = 0.f;
  }
  if (PASS == 2) {
#pragma unroll
    for (int n = 0; n < 4; ++n) {
      // untouched rows decode to NaN -> comparisons false -> hard sums stay 0 (fallback)
      thrp[n] = u2f_mono(nmaxu[grow[n]]) + 0.1f;  // pos_hard: s - MARGIN < neg_max
      thrn[n] = u2f_mono(pminu[grow[n]]) - 0.1f;  // neg_hard: s + MARGIN > pos_min
    }
  }

  for (int tt = 0; tt < CCHUNK; ++tt) {
    const int colBase = (colChunk * CCHUNK + tt) * 128;
    const bool diag = (colBase == rowBase);

    short8 av[16];  // col-operand fragments [kk*4+m]
#pragma unroll
    for (int kk = 0; kk < 4; ++kk)
#pragma unroll
      for (int m = 0; m < 4; ++m)
        av[kk * 4 + m] = *reinterpret_cast<const short8*>(
            eh + (size_t)(colBase + wc * 64 + m * 16 + l15) * NDIM + kk * 32 + g * 8);

    int lcv[4][4];
#pragma unroll
    for (int m = 0; m < 4; ++m) {
      int4 lv = *reinterpret_cast<const int4*>(labels + colBase + wc * 64 + m * 16 + g * 4);
      lcv[m][0] = lv.x; lcv[m][1] = lv.y; lcv[m][2] = lv.z; lcv[m][3] = lv.w;
    }

    f32x4 acc[4][4];
#pragma unroll
    for (int m = 0; m < 4; ++m)
#pragma unroll
      for (int n = 0; n < 4; ++n) acc[m][n] = (f32x4){0.f, 0.f, 0.f, 0.f};
#pragma unroll
    for (int kk = 0; kk < 4; ++kk)
#pragma unroll
      for (int m = 0; m < 4; ++m)
#pragma unroll
        for (int n = 0; n < 4; ++n)
          acc[m][n] = __builtin_amdgcn_mfma_f32_16x16x32_bf16(av[kk * 4 + m], bv[kk][n], acc[m][n], 0, 0, 0);

#pragma unroll
    for (int n = 0; n < 4; ++n) {
#pragma unroll
      for (int m = 0; m < 4; ++m) {
#pragma unroll
        for (int r = 0; r < 4; ++r) {
          const float s = acc[m][n][r];
          const bool eq = (lr[n] == lcv[m][r]);
          // diagonal element: same 64-half, same 16-tile, same in-tile index
          const bool dg = diag && (wr == wc) && (m == n) && (l15 == g * 4 + r);
          if (PASS == 1) {
            if (eq && !dg) pminA[n] = fminf(pminA[n], s);
            if (!eq) nmaxA[n] = fmaxf(nmaxA[n], s);
          } else {
            const float ep = exp2f(fmaf(s, -2.885390082f, 1.442695041f));   // exp(-2(s-.5))
            const float en = exp2f(fmaf(s, 72.13475205f, -36.06737602f));   // exp(50(s-.5))
            if (eq && !dg) { ap[n] += ep; if (s < thrp[n]) hp[n] += ep; }
            if (!eq)       { an[n] += en; if (s > thrn[n]) hn[n] += en; }
          }
        }
      }
    }
  }

  // block-end combine: butterfly across the 4 g-groups, then one atomic set
#pragma unroll
  for (int n = 0; n < 4; ++n) {
    if (PASS == 1) {
      float pmin = pminA[n], nmax = nmaxA[n];
      pmin = fminf(pmin, __shfl_xor(pmin, 16));
      pmin = fminf(pmin, __shfl_xor(pmin, 32));
      nmax = fmaxf(nmax, __shfl_xor(nmax, 16));
      nmax = fmaxf(nmax, __shfl_xor(nmax, 32));
      if (g == 0 && pmin < INFINITY) atomicMin(&pminu[grow[n]], f2u_mono(pmin));
      if (g == 1 && nmax > -INFINITY) atomicMax(&nmaxu[grow[n]], f2u_mono(nmax));
    } else {
      float a0 = ap[n], a1 = hp[n], a2 = an[n], a3 = hn[n];
      a0 += __shfl_xor(a0, 16); a0 += __shfl_xor(a0, 32);
      a1 += __shfl_xor(a1, 16); a1 += __shfl_xor(a1, 32);
      a2 += __shfl_xor(a2, 16); a2 += __shfl_xor(a2, 32);
      a3 += __shfl_xor(a3, 16); a3 += __shfl_xor(a3, 32);
      float v = (g == 0) ? a0 : (g == 1) ? a1 : (g == 2) ? a2 : a3;
      if (v > 0.f) atomicAdd(sums + g * NROW + grow[n], v);
    }
  }
}

__global__ __launch_bounds__(256) void k_final(const float* __restrict__ sums,
                                               float* __restrict__ out) {
  const int t = threadIdx.x;
  float acc = 0.f, cnt = 0.f;
  for (int i = t; i < NROW; i += 256) {
    float ap = sums[i], hp = sums[NROW + i], an = sums[2 * NROW + i], hn = sums[3 * NROW + i];
    bool valid = (ap > 0.f) && (an > 0.f);
    float ps = (hp > 0.f) ? hp : ap;
    float ns = (hn > 0.f) ? hn : an;
    float loss = 0.5f * log1pf(ps) + 0.02f * log1pf(ns);
    if (valid) { acc += loss; cnt += 1.f; }
  }
#pragma unroll
  for (int o = 32; o > 0; o >>= 1) {
    acc += __shfl_down(acc, o);
    cnt += __shfl_down(cnt, o);
  }
  __shared__ float sa[4], sc[4];
  int w = t >> 6, lane = t & 63;
  if (lane == 0) { sa[w] = acc; sc[w] = cnt; }
  __syncthreads();
  if (t == 0) {
    float A = sa[0] + sa[1] + sa[2] + sa[3];
    float C = sc[0] + sc[1] + sc[2] + sc[3];
    out[0] = A / fmaxf(C, 1.f);
  }
}

extern "C" void kernel_launch(void* const* d_in, const int* in_sizes, int n_in,
                              void* d_out, int out_size, void* d_ws, size_t ws_size,
                              hipStream_t stream) {
  const float* emb = (const float*)d_in[0];
  const int* labels = (const int*)d_in[1];
  float* out = (float*)d_out;

  // ws layout: [bf16 emb: 2MB][pminu:32K][nmaxu:32K][sums: 4x32K]
  unsigned short* embh = (unsigned short*)d_ws;
  unsigned* pminu = (unsigned*)((char*)d_ws + (size_t)NROW * NDIM * 2);
  unsigned* nmaxu = pminu + NROW;
  float* sums = (float*)(nmaxu + NROW);

  hipMemsetAsync(pminu, 0xFF, (size_t)NROW * 4, stream);   // mapped +inf sentinel
  hipMemsetAsync(nmaxu, 0, (size_t)NROW * 4 * 5, stream);  // nmaxu + 4 sums = 0

  k_convert<<<NROW * NDIM / (256 * 8), 256, 0, stream>>>(emb, embh);
  dim3 grid(CCHUNK, 64);
  k_sim<1><<<grid, 256, 0, stream>>>(embh, labels, pminu, nmaxu, sums);
  k_sim<2><<<grid, 256, 0, stream>>>(embh, labels, pminu, nmaxu, sums);
  k_final<<<1, 256, 0, stream>>>(sums, out);
}